// Round 3
// baseline (1173.828 us; speedup 1.0000x reference)
//
#include <hip/hip_runtime.h>
#include <math.h>

// B=2, T=1024, C=4096, Hq=32, Hkv=8, D=128, G=4, cache len 4096, start_pos on device.
// I/O is fp32 (per reference); compute is bf16 MFMA with fp32 accumulate.
// ws usage: 16.8 MB (bf16 ctx only). Pre-RoPE q lives in d_out (exact 33.5 MB fit).

typedef __bf16 bf16x8 __attribute__((ext_vector_type(8)));
typedef float floatx4 __attribute__((ext_vector_type(4)));

__device__ __forceinline__ unsigned short f2bf(float f) {
  union { float f; unsigned int u; } v; v.f = f;
  unsigned int u = v.u;
  return (unsigned short)((u + 0x7fffu + ((u >> 16) & 1u)) >> 16);
}

__device__ __forceinline__ bf16x8 pack8(float4 a, float4 b) {
  bf16x8 v;
  v[0] = (__bf16)a.x; v[1] = (__bf16)a.y; v[2] = (__bf16)a.z; v[3] = (__bf16)a.w;
  v[4] = (__bf16)b.x; v[5] = (__bf16)b.y; v[6] = (__bf16)b.z; v[7] = (__bf16)b.w;
  return v;
}

// ---------------------------------------------------------------------------
// GEMM: C[m][n] = sum_k A[m][k] * B[n][k]  (row-major, K contiguous), fp32 out.
// A: fp32 (or bf16 if ABF16), B: fp32; both cvt->bf16 during LDS staging.
// MODE 0: plain output rows. MODE 1: KV-cache scatter: m=b*1024+t -> row b*4096+sp+t.
// 128x128 tile, BK=32, 4 waves (2x2 of 64x64), mfma_f32_16x16x32_bf16.
// A-frag: lane holds A[m=lane&15][k=quad*8+j]; B-frag: B[n=lane&15][k=quad*8+j]
// C/D: row=(lane>>4)*4+r (m side), col=lane&15 (n side).
// ---------------------------------------------------------------------------
template<int MODE, bool ABF16>
__global__ __launch_bounds__(256) void gemm_bt(const void* __restrict__ A_,
                                               const float* __restrict__ B,
                                               float* __restrict__ Cout,
                                               int K, int ldC,
                                               const int* __restrict__ spp) {
  __shared__ __align__(16) unsigned short la[128 * 40];
  __shared__ __align__(16) unsigned short lb[128 * 40];
  const int tid = threadIdx.x;
  const int lane = tid & 63;
  const int wv = tid >> 6;
  const int quad = lane >> 4, l16 = lane & 15;
  const int wm = (wv >> 1) * 64, wn = (wv & 1) * 64;
  const int m0 = blockIdx.y * 128, n0 = blockIdx.x * 128;
  const int sp = (MODE == 1) ? spp[0] : 0;

  floatx4 acc[4][4] = {};

  // staging: 512 chunks of 8 elems per operand; chunk c -> row=c>>2, kc=(c&3)*8
  const int r0 = tid >> 2, kc0 = (tid & 3) * 8;
  const int r1 = (tid + 256) >> 2, kc1 = ((tid + 256) & 3) * 8;
  const float* b0 = B + (size_t)(n0 + r0) * K + kc0;
  const float* b1 = B + (size_t)(n0 + r1) * K + kc1;

  const float* af0 = ABF16 ? nullptr : (const float*)A_ + (size_t)(m0 + r0) * K + kc0;
  const float* af1 = ABF16 ? nullptr : (const float*)A_ + (size_t)(m0 + r1) * K + kc1;
  const unsigned short* ah0 = ABF16 ? (const unsigned short*)A_ + (size_t)(m0 + r0) * K + kc0 : nullptr;
  const unsigned short* ah1 = ABF16 ? (const unsigned short*)A_ + (size_t)(m0 + r1) * K + kc1 : nullptr;

  for (int k0 = 0; k0 < K; k0 += 32) {
    bf16x8 va0, va1;
    if (ABF16) {
      va0 = *(const bf16x8*)(ah0 + k0);
      va1 = *(const bf16x8*)(ah1 + k0);
    } else {
      va0 = pack8(*(const float4*)(af0 + k0), *(const float4*)(af0 + k0 + 4));
      va1 = pack8(*(const float4*)(af1 + k0), *(const float4*)(af1 + k0 + 4));
    }
    bf16x8 vb0 = pack8(*(const float4*)(b0 + k0), *(const float4*)(b0 + k0 + 4));
    bf16x8 vb1 = pack8(*(const float4*)(b1 + k0), *(const float4*)(b1 + k0 + 4));
    *(bf16x8*)(la + r0 * 40 + kc0) = va0;
    *(bf16x8*)(la + r1 * 40 + kc1) = va1;
    *(bf16x8*)(lb + r0 * 40 + kc0) = vb0;
    *(bf16x8*)(lb + r1 * 40 + kc1) = vb1;
    __syncthreads();
    bf16x8 af[4], bfr[4];
#pragma unroll
    for (int mi = 0; mi < 4; ++mi)
      af[mi] = *(const bf16x8*)(la + (wm + mi * 16 + l16) * 40 + quad * 8);
#pragma unroll
    for (int ni = 0; ni < 4; ++ni)
      bfr[ni] = *(const bf16x8*)(lb + (wn + ni * 16 + l16) * 40 + quad * 8);
#pragma unroll
    for (int mi = 0; mi < 4; ++mi)
#pragma unroll
      for (int ni = 0; ni < 4; ++ni)
        acc[mi][ni] = __builtin_amdgcn_mfma_f32_16x16x32_bf16(af[mi], bfr[ni], acc[mi][ni], 0, 0, 0);
    __syncthreads();
  }

#pragma unroll
  for (int mi = 0; mi < 4; ++mi) {
#pragma unroll
    for (int r = 0; r < 4; ++r) {
      const int row = m0 + wm + mi * 16 + quad * 4 + r;
      size_t rowg;
      if (MODE == 1) rowg = (size_t)((row >> 10) * 4096 + sp + (row & 1023));
      else           rowg = (size_t)row;
#pragma unroll
      for (int ni = 0; ni < 4; ++ni) {
        const int col = n0 + wn + ni * 16 + l16;
        Cout[rowg * ldC + col] = acc[mi][ni][r];
      }
    }
  }
}

// ---------------------------------------------------------------------------
// RoPE in place (fp32): q rows (2048 x 4096 in d_out), k cache rows [sp, sp+T).
// ---------------------------------------------------------------------------
__global__ __launch_bounds__(256) void rope_inplace(float* __restrict__ qb,
                                                    float* __restrict__ ck,
                                                    const int* __restrict__ spp) {
  const int m = blockIdx.x;            // b*1024 + t
  const int b = m >> 10, t = m & 1023;
  const int pos = spp[0] + t;
  const int tid = threadIdx.x;
  const float L2T = 0.2076205059304602f;  // log2(10000)/64

  for (int p = tid; p < 2048; p += 256) {
    int i = p & 63;
    float ang = (float)pos * exp2f(-(float)i * L2T);
    float s = sinf(ang), c = cosf(ang);
    size_t base = (size_t)m * 4096 + 2 * p;
    float x1 = qb[base], x2 = qb[base + 1];
    qb[base]     = x1 * c - x2 * s;
    qb[base + 1] = x1 * s + x2 * c;
  }
  for (int p = tid; p < 512; p += 256) {
    int i = p & 63;
    float ang = (float)pos * exp2f(-(float)i * L2T);
    float s = sinf(ang), c = cosf(ang);
    size_t base = ((size_t)(b * 4096 + pos)) * 1024 + 2 * p;
    float x1 = ck[base], x2 = ck[base + 1];
    ck[base]     = x1 * c - x2 * s;
    ck[base + 1] = x1 * s + x2 * c;
  }
}

// ---------------------------------------------------------------------------
// Flash attention (GQA): 64 Q-rows/block, 4 waves x 16 rows, S-tiles of 64.
// fp32 cache -> bf16 LDS staging; all-finite arithmetic; bf16 ctx out.
// ---------------------------------------------------------------------------
__global__ __launch_bounds__(256) void attn(const float* __restrict__ qb,
                                            const float* __restrict__ ck,
                                            const float* __restrict__ cv,
                                            const int* __restrict__ spp,
                                            unsigned short* __restrict__ ctx) {
  __shared__ __align__(16) unsigned short kt_lds[64 * 136];   // K tile [s][d], stride 136
  __shared__ __align__(16) unsigned short vt_lds[128 * 72];   // V^T tile [d][s], stride 72
  __shared__ __align__(16) unsigned short p_lds[4][16 * 64];  // per-wave P tile

  const int sp = spp[0];
  const int bh = blockIdx.y;
  const int b = bh >> 5, h = bh & 31;
  const int kh = h >> 2;
  const int qt = blockIdx.x;
  const int tid = threadIdx.x, lane = tid & 63, w = tid >> 6;
  const int quad = lane >> 4, l16 = lane & 15;
  const float scale = 0.08838834764831845f;  // 1/sqrt(128)
  const float NEG = -1e30f;

  bf16x8 qf[4];
  {
    const int qrow = qt * 64 + w * 16 + l16;
    const float* qbase = qb + ((size_t)(b * 1024 + qrow)) * 4096 + h * 128;
#pragma unroll
    for (int kt = 0; kt < 4; ++kt)
      qf[kt] = pack8(*(const float4*)(qbase + kt * 32 + quad * 8),
                     *(const float4*)(qbase + kt * 32 + quad * 8 + 4));
  }

  floatx4 o[8] = {};
  float mrow[4], lrow[4];
#pragma unroll
  for (int r = 0; r < 4; ++r) { mrow[r] = NEG; lrow[r] = 0.0f; }

  const int s_end = sp + qt * 64 + 64;
  const int ntiles = (s_end + 63) >> 6;

  for (int st = 0; st < ntiles; ++st) {
    const int s0 = st * 64;
    // K tile: chunk c -> s=c>>4, dc=(c&15)*8
#pragma unroll
    for (int it = 0; it < 4; ++it) {
      int c = tid + it * 256;
      int s = c >> 4, dc = (c & 15) * 8;
      const float* src = ck + ((size_t)(b * 4096 + s0 + s)) * 1024 + kh * 128 + dc;
      *(bf16x8*)(kt_lds + s * 136 + dc) = pack8(*(const float4*)src, *(const float4*)(src + 4));
    }
    // V^T tile: chunk c -> d=c&127, sg=c>>7 (gather 8 s-values)
#pragma unroll
    for (int it = 0; it < 4; ++it) {
      int c = tid + it * 256;
      int d = c & 127, sg = c >> 7;
      bf16x8 tmp;
#pragma unroll
      for (int ss = 0; ss < 8; ++ss)
        tmp[ss] = (__bf16)cv[((size_t)(b * 4096 + s0 + sg * 8 + ss)) * 1024 + kh * 128 + d];
      *(bf16x8*)(vt_lds + d * 72 + sg * 8) = tmp;
    }
    __syncthreads();

    floatx4 sfr[4];
#pragma unroll
    for (int ni = 0; ni < 4; ++ni) {
      floatx4 a = {};
#pragma unroll
      for (int kt = 0; kt < 4; ++kt) {
        bf16x8 kf = *(const bf16x8*)(kt_lds + (ni * 16 + l16) * 136 + kt * 32 + quad * 8);
        a = __builtin_amdgcn_mfma_f32_16x16x32_bf16(qf[kt], kf, a, 0, 0, 0);
      }
      sfr[ni] = a;
    }
#pragma unroll
    for (int ni = 0; ni < 4; ++ni) {
#pragma unroll
      for (int r = 0; r < 4; ++r) {
        int j = s0 + ni * 16 + l16;
        int tg = sp + qt * 64 + w * 16 + quad * 4 + r;
        float v = sfr[ni][r] * scale;
        sfr[ni][r] = (j <= tg) ? v : NEG;
      }
    }
    float mnew[4], rs[4];
#pragma unroll
    for (int r = 0; r < 4; ++r) {
      float v = fmaxf(fmaxf(sfr[0][r], sfr[1][r]), fmaxf(sfr[2][r], sfr[3][r]));
#pragma unroll
      for (int off = 1; off < 16; off <<= 1) v = fmaxf(v, __shfl_xor(v, off, 64));
      mnew[r] = fmaxf(mrow[r], v);
    }
#pragma unroll
    for (int r = 0; r < 4; ++r) {
      float s = 0.0f;
#pragma unroll
      for (int ni = 0; ni < 4; ++ni) {
        float p = __expf(sfr[ni][r] - mnew[r]);
        sfr[ni][r] = p;
        s += p;
      }
#pragma unroll
      for (int off = 1; off < 16; off <<= 1) s += __shfl_xor(s, off, 64);
      rs[r] = s;
    }
#pragma unroll
    for (int r = 0; r < 4; ++r) {
      float alpha = __expf(mrow[r] - mnew[r]);
      lrow[r] = lrow[r] * alpha + rs[r];
      mrow[r] = mnew[r];
#pragma unroll
      for (int ni = 0; ni < 8; ++ni) o[ni][r] *= alpha;
    }
    unsigned short* pw = p_lds[w];
#pragma unroll
    for (int ni = 0; ni < 4; ++ni)
#pragma unroll
      for (int r = 0; r < 4; ++r)
        pw[(quad * 4 + r) * 64 + ni * 16 + l16] = f2bf(sfr[ni][r]);
#pragma unroll
    for (int kt = 0; kt < 2; ++kt) {
      bf16x8 pf = *(const bf16x8*)(pw + l16 * 64 + kt * 32 + quad * 8);
#pragma unroll
      for (int ni = 0; ni < 8; ++ni) {
        bf16x8 vf = *(const bf16x8*)(vt_lds + (ni * 16 + l16) * 72 + kt * 32 + quad * 8);
        o[ni] = __builtin_amdgcn_mfma_f32_16x16x32_bf16(pf, vf, o[ni], 0, 0, 0);
      }
    }
    __syncthreads();
  }

#pragma unroll
  for (int r = 0; r < 4; ++r) {
    float invl = 1.0f / lrow[r];
    int t = qt * 64 + w * 16 + quad * 4 + r;
    unsigned short* cbase = ctx + ((size_t)(b * 1024 + t)) * 4096 + h * 128;
#pragma unroll
    for (int ni = 0; ni < 8; ++ni)
      cbase[ni * 16 + l16] = f2bf(o[ni][r] * invl);
  }
}

// ---------------------------------------------------------------------------
extern "C" void kernel_launch(void* const* d_in, const int* in_sizes, int n_in,
                              void* d_out, int out_size, void* d_ws, size_t ws_size,
                              hipStream_t stream) {
  const float* x  = (const float*)d_in[0];
  const int* sp   = (const int*)d_in[1];
  float* ck       = (float*)d_in[2];  // cache_keys (written in place, fp32)
  float* cv       = (float*)d_in[3];  // cache_values (written in place, fp32)
  const float* Wq = (const float*)d_in[4];
  const float* Wk = (const float*)d_in[5];
  const float* Wv = (const float*)d_in[6];
  const float* Wo = (const float*)d_in[7];
  float* out      = (float*)d_out;

  float* qb           = out;                    // pre/post-RoPE q in d_out (exact fit)
  unsigned short* ctx = (unsigned short*)d_ws;  // bf16 attention context (16.8 MB)

  gemm_bt<0, false><<<dim3(32, 16), 256, 0, stream>>>(x, Wq, qb, 4096, 4096, nullptr);
  gemm_bt<1, false><<<dim3(8, 16),  256, 0, stream>>>(x, Wk, ck, 4096, 1024, sp);
  gemm_bt<1, false><<<dim3(8, 16),  256, 0, stream>>>(x, Wv, cv, 4096, 1024, sp);

  rope_inplace<<<2048, 256, 0, stream>>>(qb, ck, sp);

  attn<<<dim3(16, 64), 256, 0, stream>>>(qb, ck, cv, sp, ctx);

  gemm_bt<0, true><<<dim3(32, 16), 256, 0, stream>>>(ctx, Wo, out, 4096, 4096, nullptr);
}

// Round 5
// 768.905 us; speedup vs baseline: 1.5266x; 1.5266x over previous
//
#include <hip/hip_runtime.h>
#include <math.h>

// B=2, T=1024, C=4096, Hq=32, Hkv=8, D=128, G=4; start_pos on device (1024).
// I/O fp32; compute bf16 MFMA. d_out doubles as bf16 scratch before the final GEMM:
//   [0 .. 16.8MB)  qb   bf16 [b*1024+t][4096]   (q, RoPE'd, pre-scaled by 1/sqrt(D)*log2e)
//   [16.8 .. 25.2) KT   bf16 [b][kh][s<2048][d]
//   [25.2 .. 33.5) VT   bf16 [b][kh][d][s<2048]
// ws: ctx bf16 16.8MB. RoPE sin/cos table (512KB) in cache_keys rows [2048,4096) of b=0 (never read).

typedef __bf16 bf16x8 __attribute__((ext_vector_type(8)));
typedef float floatx4 __attribute__((ext_vector_type(4)));

constexpr int SMAX = 2048;
constexpr size_t KT_OFF = (size_t)2 * 1024 * 4096;             // 8,388,608 shorts
constexpr size_t VT_OFF = KT_OFF + (size_t)2 * 8 * SMAX * 128; // 12,582,912 shorts

__device__ __forceinline__ unsigned short f2bf(float f) {
  union { float f; unsigned int u; } v; v.f = f;
  unsigned int u = v.u;
  return (unsigned short)((u + 0x7fffu + ((u >> 16) & 1u)) >> 16);
}

__device__ __forceinline__ bf16x8 pack8(float4 a, float4 b) {
  bf16x8 v;
  v[0] = (__bf16)a.x; v[1] = (__bf16)a.y; v[2] = (__bf16)a.z; v[3] = (__bf16)a.w;
  v[4] = (__bf16)b.x; v[5] = (__bf16)b.y; v[6] = (__bf16)b.z; v[7] = (__bf16)b.w;
  return v;
}

// --------------------------------------------------------------------------- tables
__global__ __launch_bounds__(256) void rope_prep(const int* __restrict__ spp,
                                                 float* __restrict__ tab) {
  int idx = blockIdx.x * 256 + threadIdx.x;   // 65536 entries: idx = t*64 + i
  int t = idx >> 6, i = idx & 63;
  float ang = (float)(spp[0] + t) * exp2f(-(float)i * 0.2076205059304602f);
  tab[idx] = sinf(ang);
  tab[65536 + idx] = cosf(ang);
}

// --------------------------------------------------------------------------- old cache -> bf16 KT/VT
__global__ __launch_bounds__(256) void convert_cache(const float* __restrict__ ck,
                                                     const float* __restrict__ cv,
                                                     const int* __restrict__ spp,
                                                     unsigned short* __restrict__ kt,
                                                     unsigned short* __restrict__ vt) {
  const int sp = spp[0];
  const int bk = blockIdx.y;           // b*8+kh
  const int b = bk >> 3, kh = bk & 7;
  const int s1 = blockIdx.x * 128;
  if (s1 >= sp) return;
  const int tid = threadIdx.x;
  // K: 128 s x 16 chunks of 8 d  (2048 chunks x 8 = 16384 elems)
#pragma unroll
  for (int it = 0; it < 8; ++it) {
    int c = tid + it * 256;
    int s = c >> 4, dc = (c & 15) * 8;
    if (s1 + s < sp) {
      const float* src = ck + (((size_t)(b * 4096 + s1 + s)) * 8 + kh) * 128 + dc;
      *(bf16x8*)(kt + ((size_t)bk * SMAX + s1 + s) * 128 + dc) = pack8(*(const float4*)src, *(const float4*)(src + 4));
    }
  }
  // V -> VT: 128 d x 16 s-groups of 8  (2048 chunks x 8 = 16384 elems)  [bugfix: was half-covered]
#pragma unroll
  for (int it = 0; it < 8; ++it) {
    int c = tid + it * 256;
    int d = c & 127, sg = c >> 7;
    bf16x8 tmp;
#pragma unroll
    for (int ss = 0; ss < 8; ++ss) {
      int s = s1 + sg * 8 + ss;
      tmp[ss] = (s < sp) ? (__bf16)cv[(((size_t)(b * 4096 + s)) * 8 + kh) * 128 + d] : (__bf16)0.0f;
    }
    *(bf16x8*)(vt + (size_t)bk * 128 * SMAX + (size_t)d * SMAX + s1 + sg * 8) = tmp;
  }
}

// --------------------------------------------------------------------------- fused QKV GEMM + RoPE
// C[m][n] = sum_k x[m][k]*W[n][k]; n<4096: Wq->qb (rope, scaled); 4096..5119: Wk->KT (rope); else Wv->VT.
__global__ __launch_bounds__(256) void gemm_qkv(const float* __restrict__ A,
                                                const float* __restrict__ Wq,
                                                const float* __restrict__ Wk,
                                                const float* __restrict__ Wv,
                                                unsigned short* __restrict__ qb,
                                                unsigned short* __restrict__ kt,
                                                unsigned short* __restrict__ vt,
                                                const float* __restrict__ tab,
                                                const int* __restrict__ spp) {
  __shared__ __align__(16) unsigned short la[128 * 40];
  __shared__ __align__(16) unsigned short lb[128 * 40];
  const int K = 4096;
  const int tid = threadIdx.x, lane = tid & 63, wv = tid >> 6;
  const int quad = lane >> 4, l16 = lane & 15;
  const int wm = (wv >> 1) * 64, wn = (wv & 1) * 64;
  const int m0 = blockIdx.y * 128, n0 = blockIdx.x * 128;
  const int sp = spp[0];

  const float* Bsel; int nb;
  if (n0 < 4096)      { Bsel = Wq; nb = n0; }
  else if (n0 < 5120) { Bsel = Wk; nb = n0 - 4096; }
  else                { Bsel = Wv; nb = n0 - 5120; }

  floatx4 acc[4][4] = {};
  const int r0 = tid >> 2, kc0 = (tid & 3) * 8;
  const int r1 = (tid + 256) >> 2, kc1 = ((tid + 256) & 3) * 8;
  const float* a0 = A + (size_t)(m0 + r0) * K + kc0;
  const float* a1 = A + (size_t)(m0 + r1) * K + kc1;
  const float* b0 = Bsel + (size_t)(nb + r0) * K + kc0;
  const float* b1 = Bsel + (size_t)(nb + r1) * K + kc1;

  for (int k0 = 0; k0 < K; k0 += 32) {
    bf16x8 va0 = pack8(*(const float4*)(a0 + k0), *(const float4*)(a0 + k0 + 4));
    bf16x8 va1 = pack8(*(const float4*)(a1 + k0), *(const float4*)(a1 + k0 + 4));
    bf16x8 vb0 = pack8(*(const float4*)(b0 + k0), *(const float4*)(b0 + k0 + 4));
    bf16x8 vb1 = pack8(*(const float4*)(b1 + k0), *(const float4*)(b1 + k0 + 4));
    *(bf16x8*)(la + r0 * 40 + kc0) = va0;
    *(bf16x8*)(la + r1 * 40 + kc1) = va1;
    *(bf16x8*)(lb + r0 * 40 + kc0) = vb0;
    *(bf16x8*)(lb + r1 * 40 + kc1) = vb1;
    __syncthreads();
    bf16x8 af[4], bfr[4];
#pragma unroll
    for (int mi = 0; mi < 4; ++mi)
      af[mi] = *(const bf16x8*)(la + (wm + mi * 16 + l16) * 40 + quad * 8);
#pragma unroll
    for (int ni = 0; ni < 4; ++ni)
      bfr[ni] = *(const bf16x8*)(lb + (wn + ni * 16 + l16) * 40 + quad * 8);
#pragma unroll
    for (int mi = 0; mi < 4; ++mi)
#pragma unroll
      for (int ni = 0; ni < 4; ++ni)
        acc[mi][ni] = __builtin_amdgcn_mfma_f32_16x16x32_bf16(af[mi], bfr[ni], acc[mi][ni], 0, 0, 0);
    __syncthreads();
  }

  const float S_L2E = 0.12751745f;  // (1/sqrt(128)) * log2(e)
#pragma unroll
  for (int mi = 0; mi < 4; ++mi) {
#pragma unroll
    for (int r = 0; r < 4; ++r) {
      const int row = m0 + wm + mi * 16 + quad * 4 + r;
      const int b = row >> 10, t = row & 1023;
#pragma unroll
      for (int ni = 0; ni < 4; ++ni) {
        const int col = n0 + wn + ni * 16 + l16;
        float v = acc[mi][ni][r];
        if (col < 5120) {  // q or k: RoPE (block-uniform branch)
          int dd = col & 127, i = dd >> 1;
          float sn = tab[t * 64 + i], cs = tab[65536 + t * 64 + i];
          float vp = __shfl_xor(v, 1, 64);
          float o = (dd & 1) ? (vp * sn + v * cs) : (v * cs - vp * sn);
          if (col < 4096) {
            qb[(size_t)row * 4096 + col] = f2bf(o * S_L2E);
          } else {
            int lc = col - 4096, kh = lc >> 7, d = lc & 127;
            kt[((size_t)(b * 8 + kh) * SMAX + sp + t) * 128 + d] = f2bf(o);
          }
        } else {
          int lc = col - 5120, kh = lc >> 7, d = lc & 127;
          vt[((size_t)(b * 8 + kh) * 128 + d) * SMAX + sp + t] = f2bf(v);
        }
      }
    }
  }
}

// --------------------------------------------------------------------------- flash attention v2
__global__ __launch_bounds__(256) void attn(const unsigned short* __restrict__ qb,
                                            const unsigned short* __restrict__ ktg,
                                            const unsigned short* __restrict__ vtg,
                                            const int* __restrict__ spp,
                                            unsigned short* __restrict__ ctx) {
  __shared__ __align__(16) unsigned short kt_lds[64 * 136];
  __shared__ __align__(16) unsigned short vt_lds[128 * 72];
  __shared__ __align__(16) unsigned short p_lds[4][16 * 72];

  const int sp = spp[0];
  const int bh = blockIdx.y;
  const int b = bh >> 5, h = bh & 31;
  const int bk = b * 8 + (h >> 2);
  const int qt = (int)gridDim.x - 1 - (int)blockIdx.x;  // long blocks first
  const int tid = threadIdx.x, lane = tid & 63, w = tid >> 6;
  const int quad = lane >> 4, l16 = lane & 15;
  const float NEG = -1e30f;

  bf16x8 qf[4];
  {
    const int qrow = qt * 64 + w * 16 + l16;
    const unsigned short* qbase = qb + ((size_t)(b * 1024 + qrow)) * 4096 + h * 128;
#pragma unroll
    for (int kk = 0; kk < 4; ++kk)
      qf[kk] = *(const bf16x8*)(qbase + kk * 32 + quad * 8);
  }

  floatx4 o[8] = {};
  float mrow[4], lrow[4];
#pragma unroll
  for (int r = 0; r < 4; ++r) { mrow[r] = NEG; lrow[r] = 0.0f; }

  const int s_end = sp + qt * 64 + 64;
  const int ntiles = (s_end + 63) >> 6;
  const unsigned short* ktb = ktg + (size_t)bk * SMAX * 128;
  const unsigned short* vtb = vtg + (size_t)bk * 128 * SMAX;

  for (int st = 0; st < ntiles; ++st) {
    const int s0 = st * 64;
#pragma unroll
    for (int it = 0; it < 4; ++it) {   // K tile 64s x 128d
      int c = tid + it * 256;
      int s = c >> 4, dc = (c & 15) * 8;
      *(bf16x8*)(kt_lds + s * 136 + dc) = *(const bf16x8*)(ktb + (size_t)(s0 + s) * 128 + dc);
    }
#pragma unroll
    for (int it = 0; it < 4; ++it) {   // V^T tile 128d x 64s
      int c = tid + it * 256;
      int d = c >> 3, sc = (c & 7) * 8;
      *(bf16x8*)(vt_lds + d * 72 + sc) = *(const bf16x8*)(vtb + (size_t)d * SMAX + s0 + sc);
    }
    __syncthreads();

    floatx4 sfr[4];
#pragma unroll
    for (int ni = 0; ni < 4; ++ni) {
      floatx4 a = {};
#pragma unroll
      for (int kk = 0; kk < 4; ++kk) {
        bf16x8 kf = *(const bf16x8*)(kt_lds + (ni * 16 + l16) * 136 + kk * 32 + quad * 8);
        a = __builtin_amdgcn_mfma_f32_16x16x32_bf16(qf[kk], kf, a, 0, 0, 0);
      }
      sfr[ni] = a;
    }
#pragma unroll
    for (int ni = 0; ni < 4; ++ni) {
#pragma unroll
      for (int r = 0; r < 4; ++r) {
        int j = s0 + ni * 16 + l16;
        int tg = sp + qt * 64 + w * 16 + quad * 4 + r;
        sfr[ni][r] = (j <= tg) ? sfr[ni][r] : NEG;   // scores in log2 domain (q pre-scaled)
      }
    }
    float mnew[4], rs[4];
#pragma unroll
    for (int r = 0; r < 4; ++r) {
      float v = fmaxf(fmaxf(sfr[0][r], sfr[1][r]), fmaxf(sfr[2][r], sfr[3][r]));
#pragma unroll
      for (int off = 1; off < 16; off <<= 1) v = fmaxf(v, __shfl_xor(v, off, 64));
      mnew[r] = fmaxf(mrow[r], v);
    }
#pragma unroll
    for (int r = 0; r < 4; ++r) {
      float s = 0.0f;
#pragma unroll
      for (int ni = 0; ni < 4; ++ni) {
        float p = exp2f(sfr[ni][r] - mnew[r]);
        sfr[ni][r] = p;
        s += p;
      }
#pragma unroll
      for (int off = 1; off < 16; off <<= 1) s += __shfl_xor(s, off, 64);
      rs[r] = s;
    }
#pragma unroll
    for (int r = 0; r < 4; ++r) {
      float alpha = exp2f(mrow[r] - mnew[r]);
      lrow[r] = lrow[r] * alpha + rs[r];
      mrow[r] = mnew[r];
#pragma unroll
      for (int ni = 0; ni < 8; ++ni) o[ni][r] *= alpha;
    }
    unsigned short* pw = p_lds[w];
#pragma unroll
    for (int ni = 0; ni < 4; ++ni)
#pragma unroll
      for (int r = 0; r < 4; ++r)
        pw[(quad * 4 + r) * 72 + ni * 16 + l16] = f2bf(sfr[ni][r]);
#pragma unroll
    for (int kk = 0; kk < 2; ++kk) {
      bf16x8 pf = *(const bf16x8*)(pw + l16 * 72 + kk * 32 + quad * 8);
#pragma unroll
      for (int ni = 0; ni < 8; ++ni) {
        bf16x8 vf = *(const bf16x8*)(vt_lds + (ni * 16 + l16) * 72 + kk * 32 + quad * 8);
        o[ni] = __builtin_amdgcn_mfma_f32_16x16x32_bf16(pf, vf, o[ni], 0, 0, 0);
      }
    }
    __syncthreads();
  }

#pragma unroll
  for (int r = 0; r < 4; ++r) {
    float invl = 1.0f / lrow[r];
    int t = qt * 64 + w * 16 + quad * 4 + r;
    unsigned short* cbase = ctx + ((size_t)(b * 1024 + t)) * 4096 + h * 128;
#pragma unroll
    for (int ni = 0; ni < 8; ++ni)
      cbase[ni * 16 + l16] = f2bf(o[ni][r] * invl);
  }
}

// --------------------------------------------------------------------------- final GEMM (ctx bf16 @ Wo^T -> fp32)
__global__ __launch_bounds__(256) void gemm_wo(const unsigned short* __restrict__ A,
                                               const float* __restrict__ B,
                                               float* __restrict__ Cout) {
  __shared__ __align__(16) unsigned short la[128 * 40];
  __shared__ __align__(16) unsigned short lb[128 * 40];
  const int K = 4096;
  const int tid = threadIdx.x, lane = tid & 63, wv = tid >> 6;
  const int quad = lane >> 4, l16 = lane & 15;
  const int wm = (wv >> 1) * 64, wn = (wv & 1) * 64;
  const int m0 = blockIdx.y * 128, n0 = blockIdx.x * 128;

  floatx4 acc[4][4] = {};
  const int r0 = tid >> 2, kc0 = (tid & 3) * 8;
  const int r1 = (tid + 256) >> 2, kc1 = ((tid + 256) & 3) * 8;
  const unsigned short* a0 = A + (size_t)(m0 + r0) * K + kc0;
  const unsigned short* a1 = A + (size_t)(m0 + r1) * K + kc1;
  const float* b0 = B + (size_t)(n0 + r0) * K + kc0;
  const float* b1 = B + (size_t)(n0 + r1) * K + kc1;

  for (int k0 = 0; k0 < K; k0 += 32) {
    bf16x8 va0 = *(const bf16x8*)(a0 + k0);
    bf16x8 va1 = *(const bf16x8*)(a1 + k0);
    bf16x8 vb0 = pack8(*(const float4*)(b0 + k0), *(const float4*)(b0 + k0 + 4));
    bf16x8 vb1 = pack8(*(const float4*)(b1 + k0), *(const float4*)(b1 + k0 + 4));
    *(bf16x8*)(la + r0 * 40 + kc0) = va0;
    *(bf16x8*)(la + r1 * 40 + kc1) = va1;
    *(bf16x8*)(lb + r0 * 40 + kc0) = vb0;
    *(bf16x8*)(lb + r1 * 40 + kc1) = vb1;
    __syncthreads();
    bf16x8 af[4], bfr[4];
#pragma unroll
    for (int mi = 0; mi < 4; ++mi)
      af[mi] = *(const bf16x8*)(la + (wm + mi * 16 + l16) * 40 + quad * 8);
#pragma unroll
    for (int ni = 0; ni < 4; ++ni)
      bfr[ni] = *(const bf16x8*)(lb + (wn + ni * 16 + l16) * 40 + quad * 8);
#pragma unroll
    for (int mi = 0; mi < 4; ++mi)
#pragma unroll
      for (int ni = 0; ni < 4; ++ni)
        acc[mi][ni] = __builtin_amdgcn_mfma_f32_16x16x32_bf16(af[mi], bfr[ni], acc[mi][ni], 0, 0, 0);
    __syncthreads();
  }
#pragma unroll
  for (int mi = 0; mi < 4; ++mi)
#pragma unroll
    for (int r = 0; r < 4; ++r) {
      const int row = m0 + wm + mi * 16 + quad * 4 + r;
#pragma unroll
      for (int ni = 0; ni < 4; ++ni)
        Cout[(size_t)row * 4096 + n0 + wn + ni * 16 + l16] = acc[mi][ni][r];
    }
}

// ---------------------------------------------------------------------------
extern "C" void kernel_launch(void* const* d_in, const int* in_sizes, int n_in,
                              void* d_out, int out_size, void* d_ws, size_t ws_size,
                              hipStream_t stream) {
  const float* x  = (const float*)d_in[0];
  const int* sp   = (const int*)d_in[1];
  float* ck       = (float*)d_in[2];
  const float* cv = (const float*)d_in[3];
  const float* Wq = (const float*)d_in[4];
  const float* Wk = (const float*)d_in[5];
  const float* Wv = (const float*)d_in[6];
  const float* Wo = (const float*)d_in[7];
  float* out      = (float*)d_out;

  unsigned short* qb  = (unsigned short*)d_out;
  unsigned short* kt  = (unsigned short*)d_out + KT_OFF;
  unsigned short* vt  = (unsigned short*)d_out + VT_OFF;
  unsigned short* ctx = (unsigned short*)d_ws;            // 16.8 MB (proven in R3)
  float* tab          = ck + (size_t)2048 * 1024;         // unused cache_keys tail (b=0, s>=2048)

  rope_prep<<<256, 256, 0, stream>>>(sp, tab);
  convert_cache<<<dim3(16, 16), 256, 0, stream>>>(ck, cv, sp, kt, vt);
  gemm_qkv<<<dim3(48, 16), 256, 0, stream>>>(x, Wq, Wk, Wv, qb, kt, vt, tab, sp);
  attn<<<dim3(16, 64), 256, 0, stream>>>(qb, kt, vt, sp, ctx);
  gemm_wo<<<dim3(32, 16), 256, 0, stream>>>(ctx, Wo, out);
}

// Round 6
// 699.057 us; speedup vs baseline: 1.6792x; 1.0999x over previous
//
#include <hip/hip_runtime.h>
#include <math.h>

// B=2, T=1024, C=4096, Hq=32, Hkv=8, D=128, G=4; start_pos on device (1024).
// I/O fp32; compute bf16 MFMA. d_out doubles as bf16 scratch before the final GEMM:
//   [0 .. 16.8MB)  qb   bf16 [b*1024+t][4096]   (q, RoPE'd, pre-scaled by 1/sqrt(D)*log2e)
//   [16.8 .. 25.2) KT   bf16 [b][kh][s<2048][d]
//   [25.2 .. 33.5) VT   bf16 [b][kh][d][s<2048]
// ws (full path, needs 100.7 MB): [0,16.8) xb/ctx shared | [16.8,50.3) Wq bf16 |
//   [50.3,58.7) Wk | [58.7,67.1) Wv | [67.1,100.7) Wo   (Wq/Wk/Wv contiguous = fused 6144xK)
// ws (fallback, 16.8 MB proven): [0,16.8) xb/ctx shared; weights stay fp32 (round-5 staging).
// RoPE sin/cos table (512KB) in cache_keys tail rows (b=0, s>=2048; never read).

typedef __bf16 bf16x8 __attribute__((ext_vector_type(8)));
typedef float floatx4 __attribute__((ext_vector_type(4)));

constexpr int SMAX = 2048;
constexpr size_t KT_OFF = (size_t)2 * 1024 * 4096;             // shorts
constexpr size_t VT_OFF = KT_OFF + (size_t)2 * 8 * SMAX * 128;
// ws offsets in shorts
constexpr size_t WS_XB = 0;                       // 8,388,608 shorts (16.8 MB)
constexpr size_t WS_WQ = 8388608;                 // 16,777,216 shorts
constexpr size_t WS_WK = 25165824;                // 4,194,304
constexpr size_t WS_WV = 29360128;                // 4,194,304
constexpr size_t WS_WO = 33554432;                // 16,777,216
constexpr size_t WS_FULL_BYTES = 100663296;       // 2 * (WS_WO + 16,777,216)

__device__ __forceinline__ unsigned short f2bf(float f) {
  union { float f; unsigned int u; } v; v.f = f;
  unsigned int u = v.u;
  return (unsigned short)((u + 0x7fffu + ((u >> 16) & 1u)) >> 16);
}

__device__ __forceinline__ bf16x8 pack8(float4 a, float4 b) {
  bf16x8 v;
  v[0] = (__bf16)a.x; v[1] = (__bf16)a.y; v[2] = (__bf16)a.z; v[3] = (__bf16)a.w;
  v[4] = (__bf16)b.x; v[5] = (__bf16)b.y; v[6] = (__bf16)b.z; v[7] = (__bf16)b.w;
  return v;
}

// async global(16B/lane) -> LDS DMA; dest = wave-uniform base + lane*16
__device__ __forceinline__ void gll16(const unsigned short* g, unsigned short* l) {
  __builtin_amdgcn_global_load_lds((const __attribute__((address_space(1))) void*)g,
                                   (__attribute__((address_space(3))) void*)l, 16, 0, 0);
}

// --------------------------------------------------------------------------- fp32 -> bf16 converters
__global__ __launch_bounds__(256) void cvt_x(const float* __restrict__ x,
                                             unsigned short* __restrict__ xb) {
  for (size_t c = (size_t)blockIdx.x * 256 + threadIdx.x; c < 1048576; c += (size_t)gridDim.x * 256) {
    float4 f0 = ((const float4*)x)[c * 2], f1 = ((const float4*)x)[c * 2 + 1];
    ((bf16x8*)xb)[c] = pack8(f0, f1);
  }
}

__global__ __launch_bounds__(256) void cvt_full(const float* __restrict__ x,
                                                const float* __restrict__ wq,
                                                const float* __restrict__ wk,
                                                const float* __restrict__ wv,
                                                const float* __restrict__ wo,
                                                unsigned short* __restrict__ ws) {
  const size_t n0 = 1048576, n1 = n0 + 2097152, n2 = n1 + 524288, n3 = n2 + 524288, n4 = n3 + 2097152;
  for (size_t c = (size_t)blockIdx.x * 256 + threadIdx.x; c < n4; c += (size_t)gridDim.x * 256) {
    const float* src; unsigned short* dst; size_t off;
    if (c < n0)      { src = x;  dst = ws + WS_XB; off = c; }
    else if (c < n1) { src = wq; dst = ws + WS_WQ; off = c - n0; }
    else if (c < n2) { src = wk; dst = ws + WS_WK; off = c - n1; }
    else if (c < n3) { src = wv; dst = ws + WS_WV; off = c - n2; }
    else             { src = wo; dst = ws + WS_WO; off = c - n3; }
    float4 f0 = ((const float4*)src)[off * 2], f1 = ((const float4*)src)[off * 2 + 1];
    ((bf16x8*)dst)[off] = pack8(f0, f1);
  }
}

// --------------------------------------------------------------------------- tables
__global__ __launch_bounds__(256) void rope_prep(const int* __restrict__ spp,
                                                 float* __restrict__ tab) {
  int idx = blockIdx.x * 256 + threadIdx.x;   // 65536 entries: idx = t*64 + i
  int t = idx >> 6, i = idx & 63;
  float ang = (float)(spp[0] + t) * exp2f(-(float)i * 0.2076205059304602f);
  tab[idx] = sinf(ang);
  tab[65536 + idx] = cosf(ang);
}

// --------------------------------------------------------------------------- old cache -> bf16 KT/VT
__global__ __launch_bounds__(256) void convert_cache(const float* __restrict__ ck,
                                                     const float* __restrict__ cv,
                                                     const int* __restrict__ spp,
                                                     unsigned short* __restrict__ kt,
                                                     unsigned short* __restrict__ vt) {
  const int sp = spp[0];
  const int bk = blockIdx.y;           // b*8+kh
  const int b = bk >> 3, kh = bk & 7;
  const int s1 = blockIdx.x * 128;
  if (s1 >= sp) return;
  const int tid = threadIdx.x;
#pragma unroll
  for (int it = 0; it < 8; ++it) {     // K: 2048 chunks x 8 d
    int c = tid + it * 256;
    int s = c >> 4, dc = (c & 15) * 8;
    if (s1 + s < sp) {
      const float* src = ck + (((size_t)(b * 4096 + s1 + s)) * 8 + kh) * 128 + dc;
      *(bf16x8*)(kt + ((size_t)bk * SMAX + s1 + s) * 128 + dc) = pack8(*(const float4*)src, *(const float4*)(src + 4));
    }
  }
#pragma unroll
  for (int it = 0; it < 8; ++it) {     // V -> VT: 128 d x 16 s-groups of 8
    int c = tid + it * 256;
    int d = c & 127, sg = c >> 7;
    bf16x8 tmp;
#pragma unroll
    for (int ss = 0; ss < 8; ++ss) {
      int s = s1 + sg * 8 + ss;
      tmp[ss] = (s < sp) ? (__bf16)cv[(((size_t)(b * 4096 + s)) * 8 + kh) * 128 + d] : (__bf16)0.0f;
    }
    *(bf16x8*)(vt + (size_t)bk * 128 * SMAX + (size_t)d * SMAX + s1 + sg * 8) = tmp;
  }
}

// --------------------------------------------------------------------------- unified GEMM core
// C[m][n] = sum_k A[m][k]*B[n][k]; A bf16 (staged via global_load_lds, LDS stride 32).
// BDMA: B bf16 via global_load_lds (stride 32). !BDMA: B fp32, packed to stride-40 LDS.
// EPI 0: fp32 out, ldC=4096 (Wo).  EPI 1: QKV rope/scatter epilogue (N=6144 fused).
template<bool BDMA, int EPI>
__global__ __launch_bounds__(256) void gemm_core(const unsigned short* __restrict__ A,
                                                 const unsigned short* __restrict__ Bb,
                                                 const float* __restrict__ Bq,
                                                 const float* __restrict__ Bk,
                                                 const float* __restrict__ Bv,
                                                 float* __restrict__ Cout,
                                                 unsigned short* __restrict__ qb,
                                                 unsigned short* __restrict__ kt,
                                                 unsigned short* __restrict__ vt,
                                                 const float* __restrict__ tab,
                                                 const int* __restrict__ spp) {
  constexpr int SB = BDMA ? 32 : 40;
  __shared__ __align__(16) unsigned short la[128 * 32];
  __shared__ __align__(16) unsigned short lb[128 * SB];
  const int K = 4096;
  const int tid = threadIdx.x, lane = tid & 63, wv = tid >> 6;
  const int quad = lane >> 4, l16 = lane & 15;
  const int wm = (wv >> 1) * 64, wn = (wv & 1) * 64;
  const int m0 = blockIdx.y * 128, n0 = blockIdx.x * 128;
  const int sp = spp ? spp[0] : 0;

  floatx4 acc[4][4] = {};

  // chunk c -> row=c>>2, kc=(c&3)*8; two chunks/thread/operand
  const int r0 = tid >> 2, kc0 = (tid & 3) * 8;
  const int r1 = (tid + 256) >> 2, kc1 = ((tid + 256) & 3) * 8;
  const unsigned short* a0 = A + (size_t)(m0 + r0) * K + kc0;
  const unsigned short* a1 = A + (size_t)(m0 + r1) * K + kc1;

  // B source selection
  const unsigned short* bh0 = nullptr; const unsigned short* bh1 = nullptr;
  const float* bf0 = nullptr; const float* bf1 = nullptr;
  if (BDMA) {
    bh0 = Bb + (size_t)(n0 + r0) * K + kc0;
    bh1 = Bb + (size_t)(n0 + r1) * K + kc1;
  } else {
    const float* Bf; int nb;
    if (EPI == 0)      { Bf = Bq; nb = n0; }
    else {
      if (n0 < 4096)      { Bf = Bq; nb = n0; }
      else if (n0 < 5120) { Bf = Bk; nb = n0 - 4096; }
      else                { Bf = Bv; nb = n0 - 5120; }
    }
    bf0 = Bf + (size_t)(nb + r0) * K + kc0;
    bf1 = Bf + (size_t)(nb + r1) * K + kc1;
  }

  for (int k0 = 0; k0 < K; k0 += 32) {
    gll16(a0 + k0, la + tid * 8);
    gll16(a1 + k0, la + (tid + 256) * 8);
    if (BDMA) {
      gll16(bh0 + k0, lb + tid * 8);
      gll16(bh1 + k0, lb + (tid + 256) * 8);
    } else {
      bf16x8 vb0 = pack8(*(const float4*)(bf0 + k0), *(const float4*)(bf0 + k0 + 4));
      bf16x8 vb1 = pack8(*(const float4*)(bf1 + k0), *(const float4*)(bf1 + k0 + 4));
      *(bf16x8*)(lb + r0 * 40 + kc0) = vb0;
      *(bf16x8*)(lb + r1 * 40 + kc1) = vb1;
    }
    __syncthreads();
    bf16x8 af[4], bfr[4];
#pragma unroll
    for (int mi = 0; mi < 4; ++mi)
      af[mi] = *(const bf16x8*)(la + (wm + mi * 16 + l16) * 32 + quad * 8);
#pragma unroll
    for (int ni = 0; ni < 4; ++ni)
      bfr[ni] = *(const bf16x8*)(lb + (wn + ni * 16 + l16) * SB + quad * 8);
#pragma unroll
    for (int mi = 0; mi < 4; ++mi)
#pragma unroll
      for (int ni = 0; ni < 4; ++ni)
        acc[mi][ni] = __builtin_amdgcn_mfma_f32_16x16x32_bf16(af[mi], bfr[ni], acc[mi][ni], 0, 0, 0);
    __syncthreads();
  }

  if (EPI == 0) {
#pragma unroll
    for (int mi = 0; mi < 4; ++mi)
#pragma unroll
      for (int r = 0; r < 4; ++r) {
        const int row = m0 + wm + mi * 16 + quad * 4 + r;
#pragma unroll
        for (int ni = 0; ni < 4; ++ni)
          Cout[(size_t)row * 4096 + n0 + wn + ni * 16 + l16] = acc[mi][ni][r];
      }
  } else {
    const float S_L2E = 0.12751745f;  // (1/sqrt(128)) * log2(e)
#pragma unroll
    for (int mi = 0; mi < 4; ++mi) {
#pragma unroll
      for (int r = 0; r < 4; ++r) {
        const int row = m0 + wm + mi * 16 + quad * 4 + r;
        const int b = row >> 10, t = row & 1023;
#pragma unroll
        for (int ni = 0; ni < 4; ++ni) {
          const int col = n0 + wn + ni * 16 + l16;
          float v = acc[mi][ni][r];
          if (col < 5120) {  // q or k: RoPE (block-uniform outer branch)
            int dd = col & 127, i = dd >> 1;
            float sn = tab[t * 64 + i], cs = tab[65536 + t * 64 + i];
            float vp = __shfl_xor(v, 1, 64);
            float o = (dd & 1) ? (vp * sn + v * cs) : (v * cs - vp * sn);
            if (col < 4096) {
              qb[(size_t)row * 4096 + col] = f2bf(o * S_L2E);
            } else {
              int lc = col - 4096, kh = lc >> 7, d = lc & 127;
              kt[((size_t)(b * 8 + kh) * SMAX + sp + t) * 128 + d] = f2bf(o);
            }
          } else {
            int lc = col - 5120, kh = lc >> 7, d = lc & 127;
            vt[((size_t)(b * 8 + kh) * 128 + d) * SMAX + sp + t] = f2bf(v);
          }
        }
      }
    }
  }
}

// --------------------------------------------------------------------------- flash attention (round-5, proven)
__global__ __launch_bounds__(256) void attn(const unsigned short* __restrict__ qb,
                                            const unsigned short* __restrict__ ktg,
                                            const unsigned short* __restrict__ vtg,
                                            const int* __restrict__ spp,
                                            unsigned short* __restrict__ ctx) {
  __shared__ __align__(16) unsigned short kt_lds[64 * 136];
  __shared__ __align__(16) unsigned short vt_lds[128 * 72];
  __shared__ __align__(16) unsigned short p_lds[4][16 * 72];

  const int sp = spp[0];
  const int bh = blockIdx.y;
  const int b = bh >> 5, h = bh & 31;
  const int bk = b * 8 + (h >> 2);
  const int qt = (int)gridDim.x - 1 - (int)blockIdx.x;  // long blocks first
  const int tid = threadIdx.x, lane = tid & 63, w = tid >> 6;
  const int quad = lane >> 4, l16 = lane & 15;
  const float NEG = -1e30f;

  bf16x8 qf[4];
  {
    const int qrow = qt * 64 + w * 16 + l16;
    const unsigned short* qbase = qb + ((size_t)(b * 1024 + qrow)) * 4096 + h * 128;
#pragma unroll
    for (int kk = 0; kk < 4; ++kk)
      qf[kk] = *(const bf16x8*)(qbase + kk * 32 + quad * 8);
  }

  floatx4 o[8] = {};
  float mrow[4], lrow[4];
#pragma unroll
  for (int r = 0; r < 4; ++r) { mrow[r] = NEG; lrow[r] = 0.0f; }

  const int s_end = sp + qt * 64 + 64;
  const int ntiles = (s_end + 63) >> 6;
  const unsigned short* ktb = ktg + (size_t)bk * SMAX * 128;
  const unsigned short* vtb = vtg + (size_t)bk * 128 * SMAX;

  for (int st = 0; st < ntiles; ++st) {
    const int s0 = st * 64;
#pragma unroll
    for (int it = 0; it < 4; ++it) {   // K tile 64s x 128d
      int c = tid + it * 256;
      int s = c >> 4, dc = (c & 15) * 8;
      *(bf16x8*)(kt_lds + s * 136 + dc) = *(const bf16x8*)(ktb + (size_t)(s0 + s) * 128 + dc);
    }
#pragma unroll
    for (int it = 0; it < 4; ++it) {   // V^T tile 128d x 64s
      int c = tid + it * 256;
      int d = c >> 3, sc = (c & 7) * 8;
      *(bf16x8*)(vt_lds + d * 72 + sc) = *(const bf16x8*)(vtb + (size_t)d * SMAX + s0 + sc);
    }
    __syncthreads();

    floatx4 sfr[4];
#pragma unroll
    for (int ni = 0; ni < 4; ++ni) {
      floatx4 a = {};
#pragma unroll
      for (int kk = 0; kk < 4; ++kk) {
        bf16x8 kf = *(const bf16x8*)(kt_lds + (ni * 16 + l16) * 136 + kk * 32 + quad * 8);
        a = __builtin_amdgcn_mfma_f32_16x16x32_bf16(qf[kk], kf, a, 0, 0, 0);
      }
      sfr[ni] = a;
    }
#pragma unroll
    for (int ni = 0; ni < 4; ++ni) {
#pragma unroll
      for (int r = 0; r < 4; ++r) {
        int j = s0 + ni * 16 + l16;
        int tg = sp + qt * 64 + w * 16 + quad * 4 + r;
        sfr[ni][r] = (j <= tg) ? sfr[ni][r] : NEG;   // log2-domain scores (q pre-scaled)
      }
    }
    float mnew[4], rs[4];
#pragma unroll
    for (int r = 0; r < 4; ++r) {
      float v = fmaxf(fmaxf(sfr[0][r], sfr[1][r]), fmaxf(sfr[2][r], sfr[3][r]));
#pragma unroll
      for (int off = 1; off < 16; off <<= 1) v = fmaxf(v, __shfl_xor(v, off, 64));
      mnew[r] = fmaxf(mrow[r], v);
    }
#pragma unroll
    for (int r = 0; r < 4; ++r) {
      float s = 0.0f;
#pragma unroll
      for (int ni = 0; ni < 4; ++ni) {
        float p = exp2f(sfr[ni][r] - mnew[r]);
        sfr[ni][r] = p;
        s += p;
      }
#pragma unroll
      for (int off = 1; off < 16; off <<= 1) s += __shfl_xor(s, off, 64);
      rs[r] = s;
    }
#pragma unroll
    for (int r = 0; r < 4; ++r) {
      float alpha = exp2f(mrow[r] - mnew[r]);
      lrow[r] = lrow[r] * alpha + rs[r];
      mrow[r] = mnew[r];
#pragma unroll
      for (int ni = 0; ni < 8; ++ni) o[ni][r] *= alpha;
    }
    unsigned short* pw = p_lds[w];
#pragma unroll
    for (int ni = 0; ni < 4; ++ni)
#pragma unroll
      for (int r = 0; r < 4; ++r)
        pw[(quad * 4 + r) * 72 + ni * 16 + l16] = f2bf(sfr[ni][r]);
#pragma unroll
    for (int kk = 0; kk < 2; ++kk) {
      bf16x8 pf = *(const bf16x8*)(pw + l16 * 72 + kk * 32 + quad * 8);
#pragma unroll
      for (int ni = 0; ni < 8; ++ni) {
        bf16x8 vf = *(const bf16x8*)(vt_lds + (ni * 16 + l16) * 72 + kk * 32 + quad * 8);
        o[ni] = __builtin_amdgcn_mfma_f32_16x16x32_bf16(pf, vf, o[ni], 0, 0, 0);
      }
    }
    __syncthreads();
  }

#pragma unroll
  for (int r = 0; r < 4; ++r) {
    float invl = 1.0f / lrow[r];
    int t = qt * 64 + w * 16 + quad * 4 + r;
    unsigned short* cbase = ctx + ((size_t)(b * 1024 + t)) * 4096 + h * 128;
#pragma unroll
    for (int ni = 0; ni < 8; ++ni)
      cbase[ni * 16 + l16] = f2bf(o[ni][r] * invl);
  }
}

// ---------------------------------------------------------------------------
extern "C" void kernel_launch(void* const* d_in, const int* in_sizes, int n_in,
                              void* d_out, int out_size, void* d_ws, size_t ws_size,
                              hipStream_t stream) {
  const float* x  = (const float*)d_in[0];
  const int* sp   = (const int*)d_in[1];
  float* ck       = (float*)d_in[2];
  const float* cv = (const float*)d_in[3];
  const float* Wq = (const float*)d_in[4];
  const float* Wk = (const float*)d_in[5];
  const float* Wv = (const float*)d_in[6];
  const float* Wo = (const float*)d_in[7];
  float* out      = (float*)d_out;

  unsigned short* qb  = (unsigned short*)d_out;
  unsigned short* kt  = (unsigned short*)d_out + KT_OFF;
  unsigned short* vt  = (unsigned short*)d_out + VT_OFF;
  unsigned short* ws  = (unsigned short*)d_ws;
  unsigned short* xb  = ws + WS_XB;                 // shares [0,16.8MB) with ctx (disjoint lifetime)
  unsigned short* ctx = ws + WS_XB;
  float* tab          = ck + (size_t)2048 * 1024;   // unused cache_keys tail

  const bool full = ws_size >= WS_FULL_BYTES;

  rope_prep<<<256, 256, 0, stream>>>(sp, tab);
  convert_cache<<<dim3(16, 16), 256, 0, stream>>>(ck, cv, sp, kt, vt);

  if (full) {
    cvt_full<<<2048, 256, 0, stream>>>(x, Wq, Wk, Wv, Wo, ws);
    // fused W(q|k|v) lives contiguously at WS_WQ: rows 0..6143
    gemm_core<true, 1><<<dim3(48, 16), 256, 0, stream>>>(xb, ws + WS_WQ, nullptr, nullptr, nullptr,
                                                         nullptr, qb, kt, vt, tab, sp);
    attn<<<dim3(16, 64), 256, 0, stream>>>(qb, kt, vt, sp, ctx);
    gemm_core<true, 0><<<dim3(32, 16), 256, 0, stream>>>(ctx, ws + WS_WO, nullptr, nullptr, nullptr,
                                                         out, nullptr, nullptr, nullptr, nullptr, nullptr);
  } else {
    cvt_x<<<2048, 256, 0, stream>>>(x, xb);
    gemm_core<false, 1><<<dim3(48, 16), 256, 0, stream>>>(xb, nullptr, Wq, Wk, Wv,
                                                          nullptr, qb, kt, vt, tab, sp);
    attn<<<dim3(16, 64), 256, 0, stream>>>(qb, kt, vt, sp, ctx);
    gemm_core<false, 0><<<dim3(32, 16), 256, 0, stream>>>(ctx, nullptr, Wo, nullptr, nullptr,
                                                          out, nullptr, nullptr, nullptr, nullptr, nullptr);
  }
}